// Round 3
// baseline (396.107 us; speedup 1.0000x reference)
//
#include <hip/hip_runtime.h>
#include <cstdint>
#include <cstddef>

typedef __bf16 bf16;
typedef __bf16 bf16x4 __attribute__((ext_vector_type(4)));
typedef __bf16 bf16x8 __attribute__((ext_vector_type(8)));
typedef float f32x4 __attribute__((ext_vector_type(4)));

#define B_SZ 1024
#define D_SZ 2048
#define U_SZ 4096
#define BR_SZ 4
#define N_SZ (U_SZ * BR_SZ) /* 16384 */

// workspace layout (bytes)
// wt: bf16 tiled [32 kt][16384 n][64 k]  (64 MiB)
// wa: bf16 tiled [32 kt][1024 m][64 k]   (4 MiB)
#define WS_WT 0
#define WS_A (64u * 1024u * 1024u)
#define WS_GAT (WS_A + 4u * 1024u * 1024u) // f32 [1024][4]
#define WS_H (WS_GAT + 16384u)             // f32 [32]

__device__ __forceinline__ float sigmoidf_(float x) { return 1.f / (1.f + __expf(-x)); }

__device__ __forceinline__ uint32_t pack2_(float lo, float hi) {
  union { bf16 h[2]; uint32_t u; } cv;
  cv.h[0] = (bf16)lo; cv.h[1] = (bf16)hi;
  return cv.u;
}

// K01: inputs f32 -> bf16 (tiled [kt][m][64]) + gating softmax, one block/row
__global__ void k01_prep(const float* __restrict__ in, bf16* __restrict__ wa,
                         const float* __restrict__ Wg, const float* __restrict__ bg,
                         float* __restrict__ gat, float* __restrict__ wsh) {
  int row = blockIdx.x, tid = threadIdx.x;
  if (row == 0 && tid < 32) wsh[tid] = 0.f;
  const float* ir = in + (size_t)row * D_SZ;
  float a0 = 0, a1 = 0, a2 = 0, a3 = 0;
#pragma unroll
  for (int c = 0; c < 2; c++) {
    int d = c * 1024 + tid * 4;
    float4 x = *(const float4*)(ir + d);
    bf16x4 o;
    o[0] = (bf16)x.x; o[1] = (bf16)x.y; o[2] = (bf16)x.z; o[3] = (bf16)x.w;
    *(bf16x4*)(wa + ((size_t)(d >> 6) * B_SZ + row) * 64 + (d & 63)) = o;
    const float xs[4] = {x.x, x.y, x.z, x.w};
#pragma unroll
    for (int j = 0; j < 4; j++) {
      float4 wg = ((const float4*)Wg)[d + j];
      a0 += xs[j] * wg.x; a1 += xs[j] * wg.y; a2 += xs[j] * wg.z; a3 += xs[j] * wg.w;
    }
  }
#pragma unroll
  for (int off = 32; off; off >>= 1) {
    a0 += __shfl_down(a0, off); a1 += __shfl_down(a1, off);
    a2 += __shfl_down(a2, off); a3 += __shfl_down(a3, off);
  }
  __shared__ float red[4][4];
  int wv = tid >> 6, ln = tid & 63;
  if (ln == 0) { red[wv][0] = a0; red[wv][1] = a1; red[wv][2] = a2; red[wv][3] = a3; }
  __syncthreads();
  if (tid == 0) {
    float s0 = red[0][0] + red[1][0] + red[2][0] + red[3][0] + bg[0];
    float s1 = red[0][1] + red[1][1] + red[2][1] + red[3][1] + bg[1];
    float s2 = red[0][2] + red[1][2] + red[2][2] + red[3][2] + bg[2];
    float s3 = red[0][3] + red[1][3] + red[2][3] + red[3][3] + bg[3];
    float m = fmaxf(fmaxf(s0, s1), fmaxf(s2, s3));
    float e0 = __expf(s0 - m), e1 = __expf(s1 - m), e2 = __expf(s2 - m), e3 = __expf(s3 - m);
    float inv = 1.f / (e0 + e1 + e2 + e3);
    ((float4*)gat)[row] = make_float4(e0 * inv, e1 * inv, e2 * inv, e3 * inv);
  }
}

// K2a: h_partial = avg @ W1 (atomic accumulate into wsh[32])
__global__ void k2a_h(const float* __restrict__ avg, const float* __restrict__ W1,
                      float* __restrict__ wsh) {
  int t = threadIdx.x;
  int h = t & 31, seg = t >> 5;
  int u0 = blockIdx.x * 64 + seg * 8;
  float p = 0.f;
#pragma unroll
  for (int j = 0; j < 8; j++) {
    int u = u0 + j;
    p += avg[u] * W1[u * 32 + h];
  }
  __shared__ float red[8][32];
  red[seg][h] = p;
  __syncthreads();
  if (t < 32) {
    float s = 0.f;
#pragma unroll
    for (int sg = 0; sg < 8; sg++) s += red[sg][t];
    atomicAdd(&wsh[t], s);
  }
}

// K3: wt[kt][n][64] = bf16(w[d][n]*sigmoid(delay[d][n])), d = kt*64+k.
// One 64n x 128d tile per block. 16 float4 loads in flight per thread
// (256B/lane MLP), ONE barrier, then transposed store (2KB runs per wave).
#define K3P 66
__global__ __launch_bounds__(256) void k3_wmod_t(const float* __restrict__ w,
                                                 const float* __restrict__ delay,
                                                 bf16* __restrict__ wt) {
  __shared__ uint32_t buf[64 * K3P];
  int tid = threadIdx.x;
  int n0 = blockIdx.x * 64;
  int d0 = blockIdx.y * 128;
  int n4 = tid & 15, dh = tid >> 4;  // 16 n-groups x 16 d-octets

  float4 wv[8], dv[8];
  const float* wp = w + (size_t)(d0 + dh * 8) * N_SZ + n0 + n4 * 4;
  const float* dp = delay + (size_t)(d0 + dh * 8) * N_SZ + n0 + n4 * 4;
#pragma unroll
  for (int k = 0; k < 8; k++) {
    wv[k] = *(const float4*)(wp + (size_t)k * N_SZ);
    dv[k] = *(const float4*)(dp + (size_t)k * N_SZ);
  }
#pragma unroll
  for (int k2 = 0; k2 < 4; k2++) {
    const float* f0 = (const float*)&wv[2 * k2];
    const float* f1 = (const float*)&wv[2 * k2 + 1];
    const float* g0 = (const float*)&dv[2 * k2];
    const float* g1 = (const float*)&dv[2 * k2 + 1];
#pragma unroll
    for (int j = 0; j < 4; j++) {
      float lo = f0[j] * sigmoidf_(g0[j]);
      float hi = f1[j] * sigmoidf_(g1[j]);
      buf[(n4 * 4 + j) * K3P + dh * 4 + k2] = pack2_(lo, hi);
    }
  }
  __syncthreads();
  // read back columns, store: thread t -> n = t>>2, seg = t&3 (32 d each)
  int n = tid >> 2, seg = tid & 3;
  const uint32_t* r = &buf[n * K3P + seg * 16];
  bf16* dst = wt + ((size_t)((d0 >> 6) + (seg >> 1)) * N_SZ + n0 + n) * 64 + (seg & 1) * 32;
#pragma unroll
  for (int q = 0; q < 4; q++) {
    uint4 v;
    v.x = r[q * 4 + 0]; v.y = r[q * 4 + 1]; v.z = r[q * 4 + 2]; v.w = r[q * 4 + 3];
    *(uint4*)(dst + q * 8) = v;
  }
}

// K4: GEMM [1024,2048]x[2048,16384] bf16 MFMA, tiled A/B global layout,
// XOR-swizzled LDS, XCD-aware bid swizzle. Epilogue: +bias, gating-contract
// over BR=4, connectivity-MLP, mask, relu -> out [1024][4096] f32.
__global__ __launch_bounds__(256, 2) void k4_gemm(
    const bf16* __restrict__ A, const bf16* __restrict__ Bt,
    const float* __restrict__ gating, const float* __restrict__ bias,
    const float* __restrict__ wsh, const float* __restrict__ b1,
    const float* __restrict__ W2, const float* __restrict__ b2,
    const float* __restrict__ mask, float* __restrict__ out) {
  __shared__ bf16 Al[128 * 64];
  __shared__ bf16 Bl[128 * 64];
  __shared__ float gat[128 * 4];
  __shared__ float conn_l[32];
  int tid = threadIdx.x;
  int lane = tid & 63, wave = tid >> 6;
  // XCD swizzle: bid%8 = XCD; each XCD owns 16 nt columns, iterates mt fastest
  int bid = blockIdx.x;
  int xcd = bid & 7, p = bid >> 3;
  int mt = p & 7, nt = (xcd << 4) | (p >> 3);
  int m0 = mt * 128, n0 = nt * 128;
  int wm = (wave & 1) * 64, wn = (wave >> 1) * 64;
  int quad = lane >> 4, row16 = lane & 15;
  int r7 = row16 & 7;

  f32x4 acc[4][4];
  const f32x4 z4 = {0.f, 0.f, 0.f, 0.f};
#pragma unroll
  for (int i = 0; i < 4; i++)
#pragma unroll
    for (int j = 0; j < 4; j++) acc[i][j] = z4;

  if (tid < 128) *(float4*)&gat[tid * 4] = *(const float4*)&gating[(m0 + tid) * 4];
  if (tid < 32) {
    int u = (n0 >> 2) + tid;
    float s = b2[u];
#pragma unroll
    for (int h = 0; h < 32; h++) s += fmaxf(wsh[h] + b1[h], 0.f) * W2[h * U_SZ + u];
    conn_l[tid] = sigmoidf_(s) * mask[u];
  }

  int srow = lane >> 3;
  int scol = ((lane & 7) ^ srow) * 8;  // XOR-swizzled 16B chunk
  for (int kt = 0; kt < 32; kt++) {
#pragma unroll
    for (int c = 0; c < 4; c++) {
      int rb = wave * 32 + c * 8;
      const bf16* ga = A + ((size_t)kt * B_SZ + m0 + rb + srow) * 64 + scol;
      __builtin_amdgcn_global_load_lds(
          (const __attribute__((address_space(1))) void*)ga,
          (__attribute__((address_space(3))) void*)(Al + rb * 64), 16, 0, 0);
      const bf16* gb = Bt + ((size_t)kt * N_SZ + n0 + rb + srow) * 64 + scol;
      __builtin_amdgcn_global_load_lds(
          (const __attribute__((address_space(1))) void*)gb,
          (__attribute__((address_space(3))) void*)(Bl + rb * 64), 16, 0, 0);
    }
    __syncthreads();
#pragma unroll
    for (int kk = 0; kk < 64; kk += 32) {
      int csw = (((kk >> 3) + quad) ^ r7) * 8;  // un-swizzle chunk
      bf16x8 af[4], bfr[4];
#pragma unroll
      for (int i = 0; i < 4; i++)
        af[i] = *(const bf16x8*)&Al[(wm + i * 16 + row16) * 64 + csw];
#pragma unroll
      for (int j = 0; j < 4; j++)
        bfr[j] = *(const bf16x8*)&Bl[(wn + j * 16 + row16) * 64 + csw];
#pragma unroll
      for (int i = 0; i < 4; i++)
#pragma unroll
        for (int j = 0; j < 4; j++)
          acc[i][j] = __builtin_amdgcn_mfma_f32_16x16x32_bf16(af[i], bfr[j], acc[i][j], 0, 0, 0);
    }
    __syncthreads();
  }

  // epilogue: C layout col=lane&15, row=quad*4+reg. n = u*4+k, k = lane&3.
  int k = lane & 3;
#pragma unroll
  for (int j = 0; j < 4; j++) {
    int n_l = wn + j * 16 + row16;
    int n_g = n0 + n_l;
    int u = n_g >> 2;
    float bv = bias[n_g];
    float cv = conn_l[n_l >> 2];
#pragma unroll
    for (int i = 0; i < 4; i++) {
#pragma unroll
      for (int r = 0; r < 4; r++) {
        int r_l = wm + i * 16 + quad * 4 + r;
        float g = gat[r_l * 4 + k];
        float v = (acc[i][j][r] + bv) * g;
        v += __shfl_xor(v, 1);
        v += __shfl_xor(v, 2);
        if (k == 0) out[(size_t)(m0 + r_l) * U_SZ + u] = fmaxf(v * cv, 0.f);
      }
    }
  }
}

extern "C" void kernel_launch(void* const* d_in, const int* in_sizes, int n_in,
                              void* d_out, int out_size, void* d_ws, size_t ws_size,
                              hipStream_t stream) {
  const float* inputs = (const float*)d_in[0];
  const float* w = (const float*)d_in[1];
  const float* bb = (const float*)d_in[2];
  const float* delay = (const float*)d_in[3];
  const float* Wg = (const float*)d_in[4];
  const float* bg = (const float*)d_in[5];
  const float* W1 = (const float*)d_in[6];
  const float* b1 = (const float*)d_in[7];
  const float* W2 = (const float*)d_in[8];
  const float* b2 = (const float*)d_in[9];
  const float* mask = (const float*)d_in[10];
  const float* avg = (const float*)d_in[11];
  float* out = (float*)d_out;
  char* ws = (char*)d_ws;
  bf16* wt = (bf16*)(ws + WS_WT);
  bf16* wa = (bf16*)(ws + WS_A);
  float* gat = (float*)(ws + WS_GAT);
  float* wsh = (float*)(ws + WS_H);

  hipLaunchKernelGGL(k01_prep, dim3(B_SZ), dim3(256), 0, stream, inputs, wa, Wg, bg, gat, wsh);
  hipLaunchKernelGGL(k2a_h, dim3(U_SZ / 64), dim3(256), 0, stream, avg, W1, wsh);
  hipLaunchKernelGGL(k3_wmod_t, dim3(N_SZ / 64, D_SZ / 128), dim3(256), 0, stream, w, delay, wt);
  hipLaunchKernelGGL(k4_gemm, dim3((B_SZ / 128) * (N_SZ / 128)), dim3(256), 0, stream, wa, wt, gat, bb, wsh, b1, W2, b2, mask, out);
}